// Round 2
// baseline (1563.269 us; speedup 1.0000x reference)
//
#include <hip/hip_runtime.h>

#define N_NODES 50000
#define E_EDGES 800000
#define NEG_SLOPE 0.2f

typedef __attribute__((ext_vector_type(8))) short bf16x8;
typedef __attribute__((ext_vector_type(4))) float f32x4;

// truncate-split: f ~= hi + lo with |err| <= 2^-16 |f|
__device__ __forceinline__ void split_bf(float f, unsigned short& h, unsigned short& l) {
    unsigned u = __float_as_uint(f);
    h = (unsigned short)(u >> 16);
    float r = f - __uint_as_float((unsigned)h << 16);
    l = (unsigned short)(__float_as_uint(r) >> 16);
}

// ---------------- CSR build ----------------

__global__ void k_hist(const int* __restrict__ dst, int* __restrict__ deg) {
    int i = blockIdx.x * blockDim.x + threadIdx.x;
    if (i < E_EDGES) atomicAdd(&deg[dst[i]], 1);
}

__global__ void k_scanA(const int* __restrict__ deg, int* __restrict__ rowptr,
                        int* __restrict__ bsum, int n) {
    __shared__ int lds[256];
    int t = threadIdx.x;
    int i = blockIdx.x * 256 + t;
    int v = (i < n) ? deg[i] : 0;
    lds[t] = v;
    __syncthreads();
    for (int off = 1; off < 256; off <<= 1) {
        int u = (t >= off) ? lds[t - off] : 0;
        __syncthreads();
        lds[t] += u;
        __syncthreads();
    }
    if (i < n) rowptr[i + 1] = lds[t];
    if (t == 255) bsum[blockIdx.x] = lds[255];
}

__global__ void k_scanB(const int* __restrict__ bsum, int* __restrict__ boff, int nb) {
    __shared__ int lds[256];
    int t = threadIdx.x;
    int v = (t < nb) ? bsum[t] : 0;
    lds[t] = v;
    __syncthreads();
    for (int off = 1; off < 256; off <<= 1) {
        int u = (t >= off) ? lds[t - off] : 0;
        __syncthreads();
        lds[t] += u;
        __syncthreads();
    }
    if (t < nb) boff[t] = lds[t] - v;
}

__global__ void k_scanC(const int* __restrict__ deg, const int* __restrict__ boff,
                        int* __restrict__ rowptr, int* __restrict__ cursor, int n) {
    int i = blockIdx.x * blockDim.x + threadIdx.x;
    if (i >= n) return;
    int v = rowptr[i + 1] + boff[i >> 8];
    rowptr[i + 1] = v;
    cursor[i] = v - deg[i];
    if (i == 0) rowptr[0] = 0;
}

__global__ void k_scatter(const int* __restrict__ src, const int* __restrict__ dst,
                          int* __restrict__ cursor, int* __restrict__ csr_src) {
    int i = blockIdx.x * blockDim.x + threadIdx.x;
    if (i >= E_EDGES) return;
    int d = dst[i];
    int pos = atomicAdd(&cursor[d], 1);
    csr_src[pos] = src[i];
}

// ---------------- split-bf16 MFMA GEMM: C[M,Nc] = A[M,256] * B[256,Nc] ----------------
// BM=128, BK=32, 4 waves; wave w owns rows [32w,32w+32) (2 row-tiles of 16), all BN cols.
// fp32 staged -> hi/lo bf16 in LDS; 3 MFMAs (HH, HL, LH) per fragment pair.

template<int BN>
__global__ __launch_bounds__(256) void mfma_gemm(const float* __restrict__ A,
                                                 const float* __restrict__ B,
                                                 float* __restrict__ C,
                                                 int M, int Nc) {
    constexpr int K = 256;
    constexpr int CT = BN / 16;     // col tiles per block
    constexpr int BF4 = BN / 4;     // float4s per B row
    constexpr int BKS = 256 / BF4;  // k-rows covered per staging pass
    __shared__ __align__(16) unsigned short AsH[128][40];
    __shared__ __align__(16) unsigned short AsL[128][40];
    __shared__ __align__(16) unsigned short BsH[BN][40];   // transposed: [col][k]
    __shared__ __align__(16) unsigned short BsL[BN][40];

    const int t = threadIdx.x;
    const int w = t >> 6;
    const int lane = t & 63;
    const int r16 = lane & 15;
    const int kg = lane >> 4;
    const int bm = blockIdx.x * 128;
    const int bn = blockIdx.y * BN;

    const int ar0 = t >> 3;         // 0..31
    const int acol = (t & 7) * 4;   // 0..28
    const int bcf4 = (t % BF4) * 4; // B col
    const int bk0 = t / BF4;        // B k row

    f32x4 acc[2][CT];
#pragma unroll
    for (int i = 0; i < 2; ++i)
#pragma unroll
        for (int j = 0; j < CT; ++j) acc[i][j] = (f32x4){0.f, 0.f, 0.f, 0.f};

    for (int k0 = 0; k0 < K; k0 += 32) {
        // stage A 128x32
#pragma unroll
        for (int rr = 0; rr < 4; ++rr) {
            int row = ar0 + 32 * rr;
            int grow = bm + row;
            float4 v = make_float4(0.f, 0.f, 0.f, 0.f);
            if (grow < M) v = *(const float4*)&A[(size_t)grow * K + k0 + acol];
            unsigned short h0, h1, h2, h3, l0, l1, l2, l3;
            split_bf(v.x, h0, l0); split_bf(v.y, h1, l1);
            split_bf(v.z, h2, l2); split_bf(v.w, h3, l3);
            *(uint2*)&AsH[row][acol] = make_uint2((unsigned)h0 | ((unsigned)h1 << 16),
                                                  (unsigned)h2 | ((unsigned)h3 << 16));
            *(uint2*)&AsL[row][acol] = make_uint2((unsigned)l0 | ((unsigned)l1 << 16),
                                                  (unsigned)l2 | ((unsigned)l3 << 16));
        }
        // stage B 32xBN transposed
#pragma unroll
        for (int kk = bk0; kk < 32; kk += BKS) {
            float4 v = *(const float4*)&B[(size_t)(k0 + kk) * Nc + bn + bcf4];
            unsigned short h, l;
            split_bf(v.x, h, l); BsH[bcf4 + 0][kk] = h; BsL[bcf4 + 0][kk] = l;
            split_bf(v.y, h, l); BsH[bcf4 + 1][kk] = h; BsL[bcf4 + 1][kk] = l;
            split_bf(v.z, h, l); BsH[bcf4 + 2][kk] = h; BsL[bcf4 + 2][kk] = l;
            split_bf(v.w, h, l); BsH[bcf4 + 3][kk] = h; BsL[bcf4 + 3][kk] = l;
        }
        __syncthreads();

        bf16x8 aH[2], aL[2];
#pragma unroll
        for (int rt = 0; rt < 2; ++rt) {
            aH[rt] = *(const bf16x8*)&AsH[w * 32 + rt * 16 + r16][kg * 8];
            aL[rt] = *(const bf16x8*)&AsL[w * 32 + rt * 16 + r16][kg * 8];
        }
#pragma unroll
        for (int ct = 0; ct < CT; ++ct) {
            const bf16x8 bH = *(const bf16x8*)&BsH[ct * 16 + r16][kg * 8];
            const bf16x8 bL = *(const bf16x8*)&BsL[ct * 16 + r16][kg * 8];
#pragma unroll
            for (int rt = 0; rt < 2; ++rt) {
                acc[rt][ct] = __builtin_amdgcn_mfma_f32_16x16x32_bf16(aH[rt], bH, acc[rt][ct], 0, 0, 0);
                acc[rt][ct] = __builtin_amdgcn_mfma_f32_16x16x32_bf16(aH[rt], bL, acc[rt][ct], 0, 0, 0);
                acc[rt][ct] = __builtin_amdgcn_mfma_f32_16x16x32_bf16(aL[rt], bH, acc[rt][ct], 0, 0, 0);
            }
        }
        __syncthreads();
    }

#pragma unroll
    for (int rt = 0; rt < 2; ++rt)
#pragma unroll
        for (int r = 0; r < 4; ++r) {
            int row = bm + w * 32 + rt * 16 + kg * 4 + r;
            if (row < M) {
#pragma unroll
                for (int ct = 0; ct < CT; ++ct)
                    C[(size_t)row * Nc + bn + ct * 16 + r16] = acc[rt][ct][r];
            }
        }
}

// ---------------- fused GATv2 edge-softmax + aggregation ----------------
// Persistent waves, atomic work-stealing over nodes, 2 edges/iter.

__global__ __launch_bounds__(256) void gat_edge0(const float* __restrict__ feat,
                                                 const float* __restrict__ attn,
                                                 const int* __restrict__ rowptr,
                                                 const int* __restrict__ csr,
                                                 float* __restrict__ out,
                                                 int* __restrict__ counter) {
    const int lane = threadIdx.x & 63;
    const int dbase = ((lane >> 4) << 6) + (lane & 15) * 4;  // head*64 + sub*4
    const float4 a = *(const float4*)&attn[dbase];
    for (;;) {
        int node;
        if (lane == 0) node = atomicAdd(counter, 1);
        node = __shfl(node, 0);
        if (node >= N_NODES) return;
        const float4 fd = *(const float4*)&feat[(size_t)node * 256 + dbase];
        const int beg = rowptr[node], end = rowptr[node + 1];
        float m = -1e30f, s = 0.f;
        float ax = 0.f, ay = 0.f, az = 0.f, aw = 0.f;
        int j = beg;
        for (; j + 1 < end; j += 2) {
            int sn1 = csr[j], sn2 = csr[j + 1];
            float4 f1 = *(const float4*)&feat[(size_t)sn1 * 256 + dbase];
            float4 f2 = *(const float4*)&feat[(size_t)sn2 * 256 + dbase];
            float t0, t1, t2, t3;
            t0 = f1.x + fd.x; t0 = (t0 > 0.f) ? t0 : NEG_SLOPE * t0;
            t1 = f1.y + fd.y; t1 = (t1 > 0.f) ? t1 : NEG_SLOPE * t1;
            t2 = f1.z + fd.z; t2 = (t2 > 0.f) ? t2 : NEG_SLOPE * t2;
            t3 = f1.w + fd.w; t3 = (t3 > 0.f) ? t3 : NEG_SLOPE * t3;
            float p1 = t0 * a.x + t1 * a.y + t2 * a.z + t3 * a.w;
            t0 = f2.x + fd.x; t0 = (t0 > 0.f) ? t0 : NEG_SLOPE * t0;
            t1 = f2.y + fd.y; t1 = (t1 > 0.f) ? t1 : NEG_SLOPE * t1;
            t2 = f2.z + fd.z; t2 = (t2 > 0.f) ? t2 : NEG_SLOPE * t2;
            t3 = f2.w + fd.w; t3 = (t3 > 0.f) ? t3 : NEG_SLOPE * t3;
            float p2 = t0 * a.x + t1 * a.y + t2 * a.z + t3 * a.w;
            p1 += __shfl_xor(p1, 1); p2 += __shfl_xor(p2, 1);
            p1 += __shfl_xor(p1, 2); p2 += __shfl_xor(p2, 2);
            p1 += __shfl_xor(p1, 4); p2 += __shfl_xor(p2, 4);
            p1 += __shfl_xor(p1, 8); p2 += __shfl_xor(p2, 8);
            float nm = fmaxf(m, fmaxf(p1, p2));
            float c  = __expf(m - nm);
            float e1 = __expf(p1 - nm);
            float e2 = __expf(p2 - nm);
            s  = s  * c + e1 + e2;
            ax = ax * c + e1 * f1.x + e2 * f2.x;
            ay = ay * c + e1 * f1.y + e2 * f2.y;
            az = az * c + e1 * f1.z + e2 * f2.z;
            aw = aw * c + e1 * f1.w + e2 * f2.w;
            m = nm;
        }
        if (j < end) {
            int sn = csr[j];
            float4 fs = *(const float4*)&feat[(size_t)sn * 256 + dbase];
            float t0 = fs.x + fd.x; t0 = (t0 > 0.f) ? t0 : NEG_SLOPE * t0;
            float t1 = fs.y + fd.y; t1 = (t1 > 0.f) ? t1 : NEG_SLOPE * t1;
            float t2 = fs.z + fd.z; t2 = (t2 > 0.f) ? t2 : NEG_SLOPE * t2;
            float t3 = fs.w + fd.w; t3 = (t3 > 0.f) ? t3 : NEG_SLOPE * t3;
            float p = t0 * a.x + t1 * a.y + t2 * a.z + t3 * a.w;
            p += __shfl_xor(p, 1);
            p += __shfl_xor(p, 2);
            p += __shfl_xor(p, 4);
            p += __shfl_xor(p, 8);
            float nm = fmaxf(m, p);
            float c  = __expf(m - nm);
            float e  = __expf(p - nm);
            s  = s  * c + e;
            ax = ax * c + e * fs.x;
            ay = ay * c + e * fs.y;
            az = az * c + e * fs.z;
            aw = aw * c + e * fs.w;
        }
        float inv = (end > beg) ? (1.0f / s) : 0.f;
        float4 o;
        float v;
        v = ax * inv; o.x = (v > 0.f) ? v : (__expf(v) - 1.f);
        v = ay * inv; o.y = (v > 0.f) ? v : (__expf(v) - 1.f);
        v = az * inv; o.z = (v > 0.f) ? v : (__expf(v) - 1.f);
        v = aw * inv; o.w = (v > 0.f) ? v : (__expf(v) - 1.f);
        *(float4*)&out[(size_t)node * 256 + dbase] = o;
    }
}

__global__ __launch_bounds__(256) void gat_edge1(const float* __restrict__ feat,
                                                 const float* __restrict__ attn,
                                                 const int* __restrict__ rowptr,
                                                 const int* __restrict__ csr,
                                                 float* __restrict__ out,
                                                 int* __restrict__ counter) {
    const int lane = threadIdx.x & 63;
    const float a = attn[lane];
    for (;;) {
        int node;
        if (lane == 0) node = atomicAdd(counter, 1);
        node = __shfl(node, 0);
        if (node >= N_NODES) return;
        const float fd = feat[(size_t)node * 64 + lane];
        const int beg = rowptr[node], end = rowptr[node + 1];
        float m = -1e30f, s = 0.f, acc = 0.f;
        int j = beg;
        for (; j + 1 < end; j += 2) {
            int sn1 = csr[j], sn2 = csr[j + 1];
            float f1 = feat[(size_t)sn1 * 64 + lane];
            float f2 = feat[(size_t)sn2 * 64 + lane];
            float u1 = f1 + fd; u1 = (u1 > 0.f) ? u1 : NEG_SLOPE * u1;
            float u2 = f2 + fd; u2 = (u2 > 0.f) ? u2 : NEG_SLOPE * u2;
            float p1 = u1 * a, p2 = u2 * a;
            p1 += __shfl_xor(p1, 1);  p2 += __shfl_xor(p2, 1);
            p1 += __shfl_xor(p1, 2);  p2 += __shfl_xor(p2, 2);
            p1 += __shfl_xor(p1, 4);  p2 += __shfl_xor(p2, 4);
            p1 += __shfl_xor(p1, 8);  p2 += __shfl_xor(p2, 8);
            p1 += __shfl_xor(p1, 16); p2 += __shfl_xor(p2, 16);
            p1 += __shfl_xor(p1, 32); p2 += __shfl_xor(p2, 32);
            float nm = fmaxf(m, fmaxf(p1, p2));
            float c  = __expf(m - nm);
            float e1 = __expf(p1 - nm);
            float e2 = __expf(p2 - nm);
            s   = s   * c + e1 + e2;
            acc = acc * c + e1 * f1 + e2 * f2;
            m = nm;
        }
        if (j < end) {
            int sn = csr[j];
            float fs = feat[(size_t)sn * 64 + lane];
            float u = fs + fd; u = (u > 0.f) ? u : NEG_SLOPE * u;
            float p = u * a;
            p += __shfl_xor(p, 1);
            p += __shfl_xor(p, 2);
            p += __shfl_xor(p, 4);
            p += __shfl_xor(p, 8);
            p += __shfl_xor(p, 16);
            p += __shfl_xor(p, 32);
            float nm = fmaxf(m, p);
            float c  = __expf(m - nm);
            float e  = __expf(p - nm);
            s   = s   * c + e;
            acc = acc * c + e * fs;
        }
        float inv = (end > beg) ? (1.0f / s) : 0.f;
        out[(size_t)node * 64 + lane] = acc * inv;
    }
}

// ---------------- launch ----------------

extern "C" void kernel_launch(void* const* d_in, const int* in_sizes, int n_in,
                              void* d_out, int out_size, void* d_ws, size_t ws_size,
                              hipStream_t stream) {
    const float* x     = (const float*)d_in[0];
    const float* W0    = (const float*)d_in[1];
    const float* attn0 = (const float*)d_in[2];
    const float* W1    = (const float*)d_in[3];
    const float* attn1 = (const float*)d_in[4];
    const int*   src0  = (const int*)d_in[5];
    const int*   dst0  = (const int*)d_in[6];
    const int*   src1  = (const int*)d_in[7];
    const int*   dst1  = (const int*)d_in[8];
    float* out = (float*)d_out;

    float* feat0 = (float*)d_ws;                       // N*256 f32
    float* h0    = feat0 + (size_t)N_NODES * 256;      // N*256 f32
    float* feat1 = feat0;                              // N*64, reuses feat0
    int* deg    = (int*)(h0 + (size_t)N_NODES * 256);  // N
    int* rowptr = deg + N_NODES;                       // N+1
    int* cursor = rowptr + N_NODES + 1;                // N
    int* bsum   = cursor + N_NODES;                    // 256
    int* boff   = bsum + 256;                          // 256
    int* cnt    = boff + 256;                          // 2
    int* csr    = cnt + 2;                             // E

    const int nb = (N_NODES + 255) / 256;

    hipMemsetAsync(cnt, 0, 2 * sizeof(int), stream);

    // ---- layer 0 ----
    mfma_gemm<128><<<dim3(391, 2), 256, 0, stream>>>(x, W0, feat0, N_NODES, 256);

    hipMemsetAsync(deg, 0, N_NODES * sizeof(int), stream);
    k_hist<<<(E_EDGES + 255) / 256, 256, 0, stream>>>(dst0, deg);
    k_scanA<<<nb, 256, 0, stream>>>(deg, rowptr, bsum, N_NODES);
    k_scanB<<<1, 256, 0, stream>>>(bsum, boff, nb);
    k_scanC<<<nb, 256, 0, stream>>>(deg, boff, rowptr, cursor, N_NODES);
    k_scatter<<<(E_EDGES + 255) / 256, 256, 0, stream>>>(src0, dst0, cursor, csr);

    gat_edge0<<<1024, 256, 0, stream>>>(feat0, attn0, rowptr, csr, h0, cnt);

    // ---- layer 1 ----
    mfma_gemm<64><<<dim3(391, 1), 256, 0, stream>>>(h0, W1, feat1, N_NODES, 64);

    hipMemsetAsync(deg, 0, N_NODES * sizeof(int), stream);
    k_hist<<<(E_EDGES + 255) / 256, 256, 0, stream>>>(dst1, deg);
    k_scanA<<<nb, 256, 0, stream>>>(deg, rowptr, bsum, N_NODES);
    k_scanB<<<1, 256, 0, stream>>>(bsum, boff, nb);
    k_scanC<<<nb, 256, 0, stream>>>(deg, boff, rowptr, cursor, N_NODES);
    k_scatter<<<(E_EDGES + 255) / 256, 256, 0, stream>>>(src1, dst1, cursor, csr);

    gat_edge1<<<1024, 256, 0, stream>>>(feat1, attn1, rowptr, csr, out, cnt + 1);
}

// Round 3
// 473.298 us; speedup vs baseline: 3.3029x; 3.3029x over previous
//
#include <hip/hip_runtime.h>

#define N_NODES 50000
#define E_EDGES 800000
#define NEG_SLOPE 0.2f

typedef __attribute__((ext_vector_type(8))) short bf16x8;
typedef __attribute__((ext_vector_type(4))) float f32x4;

// truncate-split: f ~= hi + lo with |err| <= 2^-16 |f|
__device__ __forceinline__ void split_bf(float f, unsigned short& h, unsigned short& l) {
    unsigned u = __float_as_uint(f);
    h = (unsigned short)(u >> 16);
    float r = f - __uint_as_float((unsigned)h << 16);
    l = (unsigned short)(__float_as_uint(r) >> 16);
}

// ---------------- CSR build ----------------

__global__ void k_hist(const int* __restrict__ dst, int* __restrict__ deg) {
    int i = blockIdx.x * blockDim.x + threadIdx.x;
    if (i < E_EDGES) atomicAdd(&deg[dst[i]], 1);
}

__global__ void k_scanA(const int* __restrict__ deg, int* __restrict__ rowptr,
                        int* __restrict__ bsum, int n) {
    __shared__ int lds[256];
    int t = threadIdx.x;
    int i = blockIdx.x * 256 + t;
    int v = (i < n) ? deg[i] : 0;
    lds[t] = v;
    __syncthreads();
    for (int off = 1; off < 256; off <<= 1) {
        int u = (t >= off) ? lds[t - off] : 0;
        __syncthreads();
        lds[t] += u;
        __syncthreads();
    }
    if (i < n) rowptr[i + 1] = lds[t];
    if (t == 255) bsum[blockIdx.x] = lds[255];
}

__global__ void k_scanB(const int* __restrict__ bsum, int* __restrict__ boff, int nb) {
    __shared__ int lds[256];
    int t = threadIdx.x;
    int v = (t < nb) ? bsum[t] : 0;
    lds[t] = v;
    __syncthreads();
    for (int off = 1; off < 256; off <<= 1) {
        int u = (t >= off) ? lds[t - off] : 0;
        __syncthreads();
        lds[t] += u;
        __syncthreads();
    }
    if (t < nb) boff[t] = lds[t] - v;
}

__global__ void k_scanC(const int* __restrict__ deg, const int* __restrict__ boff,
                        int* __restrict__ rowptr, int* __restrict__ cursor, int n) {
    int i = blockIdx.x * blockDim.x + threadIdx.x;
    if (i >= n) return;
    int v = rowptr[i + 1] + boff[i >> 8];
    rowptr[i + 1] = v;
    cursor[i] = v - deg[i];
    if (i == 0) rowptr[0] = 0;
}

__global__ void k_scatter(const int* __restrict__ src, const int* __restrict__ dst,
                          int* __restrict__ cursor, int* __restrict__ csr_src) {
    int i = blockIdx.x * blockDim.x + threadIdx.x;
    if (i >= E_EDGES) return;
    int d = dst[i];
    int pos = atomicAdd(&cursor[d], 1);
    csr_src[pos] = src[i];
}

// ---------------- split-bf16 MFMA GEMM: C[M,Nc] = A[M,256] * B[256,Nc] ----------------

template<int BN>
__global__ __launch_bounds__(256) void mfma_gemm(const float* __restrict__ A,
                                                 const float* __restrict__ B,
                                                 float* __restrict__ C,
                                                 int M, int Nc) {
    constexpr int K = 256;
    constexpr int CT = BN / 16;
    constexpr int BF4 = BN / 4;
    constexpr int BKS = 256 / BF4;
    __shared__ __align__(16) unsigned short AsH[128][40];
    __shared__ __align__(16) unsigned short AsL[128][40];
    __shared__ __align__(16) unsigned short BsH[BN][40];
    __shared__ __align__(16) unsigned short BsL[BN][40];

    const int t = threadIdx.x;
    const int w = t >> 6;
    const int lane = t & 63;
    const int r16 = lane & 15;
    const int kg = lane >> 4;
    const int bm = blockIdx.x * 128;
    const int bn = blockIdx.y * BN;

    const int ar0 = t >> 3;
    const int acol = (t & 7) * 4;
    const int bcf4 = (t % BF4) * 4;
    const int bk0 = t / BF4;

    f32x4 acc[2][CT];
#pragma unroll
    for (int i = 0; i < 2; ++i)
#pragma unroll
        for (int j = 0; j < CT; ++j) acc[i][j] = (f32x4){0.f, 0.f, 0.f, 0.f};

    for (int k0 = 0; k0 < K; k0 += 32) {
#pragma unroll
        for (int rr = 0; rr < 4; ++rr) {
            int row = ar0 + 32 * rr;
            int grow = bm + row;
            float4 v = make_float4(0.f, 0.f, 0.f, 0.f);
            if (grow < M) v = *(const float4*)&A[(size_t)grow * K + k0 + acol];
            unsigned short h0, h1, h2, h3, l0, l1, l2, l3;
            split_bf(v.x, h0, l0); split_bf(v.y, h1, l1);
            split_bf(v.z, h2, l2); split_bf(v.w, h3, l3);
            *(uint2*)&AsH[row][acol] = make_uint2((unsigned)h0 | ((unsigned)h1 << 16),
                                                  (unsigned)h2 | ((unsigned)h3 << 16));
            *(uint2*)&AsL[row][acol] = make_uint2((unsigned)l0 | ((unsigned)l1 << 16),
                                                  (unsigned)l2 | ((unsigned)l3 << 16));
        }
#pragma unroll
        for (int kk = bk0; kk < 32; kk += BKS) {
            float4 v = *(const float4*)&B[(size_t)(k0 + kk) * Nc + bn + bcf4];
            unsigned short h, l;
            split_bf(v.x, h, l); BsH[bcf4 + 0][kk] = h; BsL[bcf4 + 0][kk] = l;
            split_bf(v.y, h, l); BsH[bcf4 + 1][kk] = h; BsL[bcf4 + 1][kk] = l;
            split_bf(v.z, h, l); BsH[bcf4 + 2][kk] = h; BsL[bcf4 + 2][kk] = l;
            split_bf(v.w, h, l); BsH[bcf4 + 3][kk] = h; BsL[bcf4 + 3][kk] = l;
        }
        __syncthreads();

        bf16x8 aH[2], aL[2];
#pragma unroll
        for (int rt = 0; rt < 2; ++rt) {
            aH[rt] = *(const bf16x8*)&AsH[w * 32 + rt * 16 + r16][kg * 8];
            aL[rt] = *(const bf16x8*)&AsL[w * 32 + rt * 16 + r16][kg * 8];
        }
#pragma unroll
        for (int ct = 0; ct < CT; ++ct) {
            const bf16x8 bH = *(const bf16x8*)&BsH[ct * 16 + r16][kg * 8];
            const bf16x8 bL = *(const bf16x8*)&BsL[ct * 16 + r16][kg * 8];
#pragma unroll
            for (int rt = 0; rt < 2; ++rt) {
                acc[rt][ct] = __builtin_amdgcn_mfma_f32_16x16x32_bf16(aH[rt], bH, acc[rt][ct], 0, 0, 0);
                acc[rt][ct] = __builtin_amdgcn_mfma_f32_16x16x32_bf16(aH[rt], bL, acc[rt][ct], 0, 0, 0);
                acc[rt][ct] = __builtin_amdgcn_mfma_f32_16x16x32_bf16(aL[rt], bH, acc[rt][ct], 0, 0, 0);
            }
        }
        __syncthreads();
    }

#pragma unroll
    for (int rt = 0; rt < 2; ++rt)
#pragma unroll
        for (int r = 0; r < 4; ++r) {
            int row = bm + w * 32 + rt * 16 + kg * 4 + r;
            if (row < M) {
#pragma unroll
                for (int ct = 0; ct < CT; ++ct)
                    C[(size_t)row * Nc + bn + ct * 16 + r16] = acc[rt][ct][r];
            }
        }
}

// ---------------- fused GATv2 edge-softmax + aggregation ----------------
// Static wave-per-node mapping; 2 edges/iter merged online-softmax update.

__global__ __launch_bounds__(256) void gat_edge0(const float* __restrict__ feat,
                                                 const float* __restrict__ attn,
                                                 const int* __restrict__ rowptr,
                                                 const int* __restrict__ csr,
                                                 float* __restrict__ out) {
    const int lane = threadIdx.x & 63;
    const int node = blockIdx.x * 4 + (threadIdx.x >> 6);
    if (node >= N_NODES) return;
    const int dbase = ((lane >> 4) << 6) + (lane & 15) * 4;  // head*64 + sub*4
    const float4 a  = *(const float4*)&attn[dbase];
    const float4 fd = *(const float4*)&feat[(size_t)node * 256 + dbase];
    const int beg = rowptr[node], end = rowptr[node + 1];
    float m = -1e30f, s = 0.f;
    float ax = 0.f, ay = 0.f, az = 0.f, aw = 0.f;
    int j = beg;
    for (; j + 1 < end; j += 2) {
        int sn1 = csr[j], sn2 = csr[j + 1];
        float4 f1 = *(const float4*)&feat[(size_t)sn1 * 256 + dbase];
        float4 f2 = *(const float4*)&feat[(size_t)sn2 * 256 + dbase];
        float t0, t1, t2, t3;
        t0 = f1.x + fd.x; t0 = (t0 > 0.f) ? t0 : NEG_SLOPE * t0;
        t1 = f1.y + fd.y; t1 = (t1 > 0.f) ? t1 : NEG_SLOPE * t1;
        t2 = f1.z + fd.z; t2 = (t2 > 0.f) ? t2 : NEG_SLOPE * t2;
        t3 = f1.w + fd.w; t3 = (t3 > 0.f) ? t3 : NEG_SLOPE * t3;
        float p1 = t0 * a.x + t1 * a.y + t2 * a.z + t3 * a.w;
        t0 = f2.x + fd.x; t0 = (t0 > 0.f) ? t0 : NEG_SLOPE * t0;
        t1 = f2.y + fd.y; t1 = (t1 > 0.f) ? t1 : NEG_SLOPE * t1;
        t2 = f2.z + fd.z; t2 = (t2 > 0.f) ? t2 : NEG_SLOPE * t2;
        t3 = f2.w + fd.w; t3 = (t3 > 0.f) ? t3 : NEG_SLOPE * t3;
        float p2 = t0 * a.x + t1 * a.y + t2 * a.z + t3 * a.w;
        p1 += __shfl_xor(p1, 1); p2 += __shfl_xor(p2, 1);
        p1 += __shfl_xor(p1, 2); p2 += __shfl_xor(p2, 2);
        p1 += __shfl_xor(p1, 4); p2 += __shfl_xor(p2, 4);
        p1 += __shfl_xor(p1, 8); p2 += __shfl_xor(p2, 8);
        float nm = fmaxf(m, fmaxf(p1, p2));
        float c  = __expf(m - nm);
        float e1 = __expf(p1 - nm);
        float e2 = __expf(p2 - nm);
        s  = s  * c + e1 + e2;
        ax = ax * c + e1 * f1.x + e2 * f2.x;
        ay = ay * c + e1 * f1.y + e2 * f2.y;
        az = az * c + e1 * f1.z + e2 * f2.z;
        aw = aw * c + e1 * f1.w + e2 * f2.w;
        m = nm;
    }
    if (j < end) {
        int sn = csr[j];
        float4 fs = *(const float4*)&feat[(size_t)sn * 256 + dbase];
        float t0 = fs.x + fd.x; t0 = (t0 > 0.f) ? t0 : NEG_SLOPE * t0;
        float t1 = fs.y + fd.y; t1 = (t1 > 0.f) ? t1 : NEG_SLOPE * t1;
        float t2 = fs.z + fd.z; t2 = (t2 > 0.f) ? t2 : NEG_SLOPE * t2;
        float t3 = fs.w + fd.w; t3 = (t3 > 0.f) ? t3 : NEG_SLOPE * t3;
        float p = t0 * a.x + t1 * a.y + t2 * a.z + t3 * a.w;
        p += __shfl_xor(p, 1);
        p += __shfl_xor(p, 2);
        p += __shfl_xor(p, 4);
        p += __shfl_xor(p, 8);
        float nm = fmaxf(m, p);
        float c  = __expf(m - nm);
        float e  = __expf(p - nm);
        s  = s  * c + e;
        ax = ax * c + e * fs.x;
        ay = ay * c + e * fs.y;
        az = az * c + e * fs.z;
        aw = aw * c + e * fs.w;
    }
    float inv = (end > beg) ? (1.0f / s) : 0.f;
    float4 o;
    float v;
    v = ax * inv; o.x = (v > 0.f) ? v : (__expf(v) - 1.f);
    v = ay * inv; o.y = (v > 0.f) ? v : (__expf(v) - 1.f);
    v = az * inv; o.z = (v > 0.f) ? v : (__expf(v) - 1.f);
    v = aw * inv; o.w = (v > 0.f) ? v : (__expf(v) - 1.f);
    *(float4*)&out[(size_t)node * 256 + dbase] = o;
}

__global__ __launch_bounds__(256) void gat_edge1(const float* __restrict__ feat,
                                                 const float* __restrict__ attn,
                                                 const int* __restrict__ rowptr,
                                                 const int* __restrict__ csr,
                                                 float* __restrict__ out) {
    const int lane = threadIdx.x & 63;
    const int node = blockIdx.x * 4 + (threadIdx.x >> 6);
    if (node >= N_NODES) return;
    const float a  = attn[lane];
    const float fd = feat[(size_t)node * 64 + lane];
    const int beg = rowptr[node], end = rowptr[node + 1];
    float m = -1e30f, s = 0.f, acc = 0.f;
    int j = beg;
    for (; j + 1 < end; j += 2) {
        int sn1 = csr[j], sn2 = csr[j + 1];
        float f1 = feat[(size_t)sn1 * 64 + lane];
        float f2 = feat[(size_t)sn2 * 64 + lane];
        float u1 = f1 + fd; u1 = (u1 > 0.f) ? u1 : NEG_SLOPE * u1;
        float u2 = f2 + fd; u2 = (u2 > 0.f) ? u2 : NEG_SLOPE * u2;
        float p1 = u1 * a, p2 = u2 * a;
        p1 += __shfl_xor(p1, 1);  p2 += __shfl_xor(p2, 1);
        p1 += __shfl_xor(p1, 2);  p2 += __shfl_xor(p2, 2);
        p1 += __shfl_xor(p1, 4);  p2 += __shfl_xor(p2, 4);
        p1 += __shfl_xor(p1, 8);  p2 += __shfl_xor(p2, 8);
        p1 += __shfl_xor(p1, 16); p2 += __shfl_xor(p2, 16);
        p1 += __shfl_xor(p1, 32); p2 += __shfl_xor(p2, 32);
        float nm = fmaxf(m, fmaxf(p1, p2));
        float c  = __expf(m - nm);
        float e1 = __expf(p1 - nm);
        float e2 = __expf(p2 - nm);
        s   = s   * c + e1 + e2;
        acc = acc * c + e1 * f1 + e2 * f2;
        m = nm;
    }
    if (j < end) {
        int sn = csr[j];
        float fs = feat[(size_t)sn * 64 + lane];
        float u = fs + fd; u = (u > 0.f) ? u : NEG_SLOPE * u;
        float p = u * a;
        p += __shfl_xor(p, 1);
        p += __shfl_xor(p, 2);
        p += __shfl_xor(p, 4);
        p += __shfl_xor(p, 8);
        p += __shfl_xor(p, 16);
        p += __shfl_xor(p, 32);
        float nm = fmaxf(m, p);
        float c  = __expf(m - nm);
        float e  = __expf(p - nm);
        s   = s   * c + e;
        acc = acc * c + e * fs;
    }
    float inv = (end > beg) ? (1.0f / s) : 0.f;
    out[(size_t)node * 64 + lane] = acc * inv;
}

// ---------------- launch ----------------

extern "C" void kernel_launch(void* const* d_in, const int* in_sizes, int n_in,
                              void* d_out, int out_size, void* d_ws, size_t ws_size,
                              hipStream_t stream) {
    const float* x     = (const float*)d_in[0];
    const float* W0    = (const float*)d_in[1];
    const float* attn0 = (const float*)d_in[2];
    const float* W1    = (const float*)d_in[3];
    const float* attn1 = (const float*)d_in[4];
    const int*   src0  = (const int*)d_in[5];
    const int*   dst0  = (const int*)d_in[6];
    const int*   src1  = (const int*)d_in[7];
    const int*   dst1  = (const int*)d_in[8];
    float* out = (float*)d_out;

    float* feat0 = (float*)d_ws;                       // N*256 f32
    float* h0    = feat0 + (size_t)N_NODES * 256;      // N*256 f32
    float* feat1 = feat0;                              // N*64, reuses feat0
    int* deg    = (int*)(h0 + (size_t)N_NODES * 256);  // N
    int* rowptr = deg + N_NODES;                       // N+1
    int* cursor = rowptr + N_NODES + 1;                // N
    int* bsum   = cursor + N_NODES;                    // 256
    int* boff   = bsum + 256;                          // 256
    int* csr    = boff + 256;                          // E

    const int nb = (N_NODES + 255) / 256;

    // ---- layer 0 ----
    mfma_gemm<128><<<dim3(391, 2), 256, 0, stream>>>(x, W0, feat0, N_NODES, 256);

    hipMemsetAsync(deg, 0, N_NODES * sizeof(int), stream);
    k_hist<<<(E_EDGES + 255) / 256, 256, 0, stream>>>(dst0, deg);
    k_scanA<<<nb, 256, 0, stream>>>(deg, rowptr, bsum, N_NODES);
    k_scanB<<<1, 256, 0, stream>>>(bsum, boff, nb);
    k_scanC<<<nb, 256, 0, stream>>>(deg, boff, rowptr, cursor, N_NODES);
    k_scatter<<<(E_EDGES + 255) / 256, 256, 0, stream>>>(src0, dst0, cursor, csr);

    gat_edge0<<<(N_NODES + 3) / 4, 256, 0, stream>>>(feat0, attn0, rowptr, csr, h0);

    // ---- layer 1 ----
    mfma_gemm<64><<<dim3(391, 1), 256, 0, stream>>>(h0, W1, feat1, N_NODES, 64);

    hipMemsetAsync(deg, 0, N_NODES * sizeof(int), stream);
    k_hist<<<(E_EDGES + 255) / 256, 256, 0, stream>>>(dst1, deg);
    k_scanA<<<nb, 256, 0, stream>>>(deg, rowptr, bsum, N_NODES);
    k_scanB<<<1, 256, 0, stream>>>(bsum, boff, nb);
    k_scanC<<<nb, 256, 0, stream>>>(deg, boff, rowptr, cursor, N_NODES);
    k_scatter<<<(E_EDGES + 255) / 256, 256, 0, stream>>>(src1, dst1, cursor, csr);

    gat_edge1<<<(N_NODES + 3) / 4, 256, 0, stream>>>(feat1, attn1, rowptr, csr, out);
}

// Round 4
// 419.894 us; speedup vs baseline: 3.7230x; 1.1272x over previous
//
#include <hip/hip_runtime.h>

#define N_NODES 50000
#define E_EDGES 800000
#define NEG_SLOPE 0.2f

typedef __attribute__((ext_vector_type(8))) short bf16x8;
typedef __attribute__((ext_vector_type(4))) float f32x4;
typedef __attribute__((ext_vector_type(4))) _Float16 half4v;

// truncate-split: f ~= hi + lo with |err| <= 2^-16 |f|
__device__ __forceinline__ void split_bf(float f, unsigned short& h, unsigned short& l) {
    unsigned u = __float_as_uint(f);
    h = (unsigned short)(u >> 16);
    float r = f - __uint_as_float((unsigned)h << 16);
    l = (unsigned short)(__float_as_uint(r) >> 16);
}

__device__ __forceinline__ float lrelu(float t) { return (t > 0.f) ? t : NEG_SLOPE * t; }

// ---------------- fused dual-layer CSR build ----------------

__global__ void k_hist2(const int* __restrict__ dst0, const int* __restrict__ dst1,
                        int* __restrict__ deg) {
    int i = blockIdx.x * blockDim.x + threadIdx.x;
    if (i >= E_EDGES) return;
    if (blockIdx.y == 0) atomicAdd(&deg[dst0[i]], 1);
    else                 atomicAdd(&deg[N_NODES + dst1[i]], 1);
}

__global__ void k_scanA(const int* __restrict__ deg, int* __restrict__ rowptr,
                        int* __restrict__ bsum) {
    const int layer = blockIdx.y;
    const int* d = deg + layer * N_NODES;
    int* rp = rowptr + layer * (N_NODES + 1);
    int* bs = bsum + layer * 256;
    __shared__ int lds[256];
    int t = threadIdx.x;
    int i = blockIdx.x * 256 + t;
    int v = (i < N_NODES) ? d[i] : 0;
    lds[t] = v;
    __syncthreads();
    for (int off = 1; off < 256; off <<= 1) {
        int u = (t >= off) ? lds[t - off] : 0;
        __syncthreads();
        lds[t] += u;
        __syncthreads();
    }
    if (i < N_NODES) rp[i + 1] = lds[t];
    if (t == 255) bs[blockIdx.x] = lds[255];
}

__global__ void k_scanB(const int* __restrict__ bsum, int* __restrict__ boff, int nb) {
    const int layer = blockIdx.x;
    const int* bs = bsum + layer * 256;
    int* bo = boff + layer * 256;
    __shared__ int lds[256];
    int t = threadIdx.x;
    int v = (t < nb) ? bs[t] : 0;
    lds[t] = v;
    __syncthreads();
    for (int off = 1; off < 256; off <<= 1) {
        int u = (t >= off) ? lds[t - off] : 0;
        __syncthreads();
        lds[t] += u;
        __syncthreads();
    }
    if (t < nb) bo[t] = lds[t] - v;
}

__global__ void k_scanC(const int* __restrict__ deg, const int* __restrict__ boff,
                        int* __restrict__ rowptr, int* __restrict__ cursor) {
    const int layer = blockIdx.y;
    int i = blockIdx.x * blockDim.x + threadIdx.x;
    if (i >= N_NODES) return;
    const int* d = deg + layer * N_NODES;
    const int* bo = boff + layer * 256;
    int* rp = rowptr + layer * (N_NODES + 1);
    int* cur = cursor + layer * N_NODES;
    int v = rp[i + 1] + bo[i >> 8];
    rp[i + 1] = v;
    cur[i] = v - d[i];
    if (i == 0) rp[0] = 0;
}

__global__ void k_scatter2(const int* __restrict__ src0, const int* __restrict__ dst0,
                           const int* __restrict__ src1, const int* __restrict__ dst1,
                           int* __restrict__ cursor,
                           int* __restrict__ csr0, int* __restrict__ csr1) {
    int i = blockIdx.x * blockDim.x + threadIdx.x;
    if (i >= E_EDGES) return;
    if (blockIdx.y == 0) {
        int d = dst0[i];
        int pos = atomicAdd(&cursor[d], 1);
        csr0[pos] = src0[i];
    } else {
        int d = dst1[i];
        int pos = atomicAdd(&cursor[N_NODES + d], 1);
        csr1[pos] = src1[i];
    }
}

// ---------------- split-bf16 MFMA GEMM, fp16 output table ----------------
// C[M,Nc](fp16) = A[M,256] * B[256,Nc];  A is f32 or fp16 per AHALF.

template<int BN, bool AHALF>
__global__ __launch_bounds__(256) void mfma_gemm(const void* __restrict__ Av,
                                                 const float* __restrict__ B,
                                                 _Float16* __restrict__ C,
                                                 int M, int Nc) {
    constexpr int K = 256;
    constexpr int CT = BN / 16;
    constexpr int BF4 = BN / 4;
    constexpr int BKS = 256 / BF4;
    __shared__ __align__(16) unsigned short AsH[128][40];
    __shared__ __align__(16) unsigned short AsL[128][40];
    __shared__ __align__(16) unsigned short BsH[BN][40];
    __shared__ __align__(16) unsigned short BsL[BN][40];

    const int t = threadIdx.x;
    const int w = t >> 6;
    const int lane = t & 63;
    const int r16 = lane & 15;
    const int kg = lane >> 4;
    const int bm = blockIdx.x * 128;
    const int bn = blockIdx.y * BN;

    const int ar0 = t >> 3;
    const int acol = (t & 7) * 4;
    const int bcf4 = (t % BF4) * 4;
    const int bk0 = t / BF4;

    f32x4 acc[2][CT];
#pragma unroll
    for (int i = 0; i < 2; ++i)
#pragma unroll
        for (int j = 0; j < CT; ++j) acc[i][j] = (f32x4){0.f, 0.f, 0.f, 0.f};

    for (int k0 = 0; k0 < K; k0 += 32) {
#pragma unroll
        for (int rr = 0; rr < 4; ++rr) {
            int row = ar0 + 32 * rr;
            int grow = bm + row;
            float4 v = make_float4(0.f, 0.f, 0.f, 0.f);
            if (grow < M) {
                if constexpr (AHALF) {
                    const _Float16* A = (const _Float16*)Av;
                    half4v hv = *(const half4v*)&A[(size_t)grow * K + k0 + acol];
                    v = make_float4((float)hv[0], (float)hv[1], (float)hv[2], (float)hv[3]);
                } else {
                    const float* A = (const float*)Av;
                    v = *(const float4*)&A[(size_t)grow * K + k0 + acol];
                }
            }
            unsigned short h0, h1, h2, h3, l0, l1, l2, l3;
            split_bf(v.x, h0, l0); split_bf(v.y, h1, l1);
            split_bf(v.z, h2, l2); split_bf(v.w, h3, l3);
            *(uint2*)&AsH[row][acol] = make_uint2((unsigned)h0 | ((unsigned)h1 << 16),
                                                  (unsigned)h2 | ((unsigned)h3 << 16));
            *(uint2*)&AsL[row][acol] = make_uint2((unsigned)l0 | ((unsigned)l1 << 16),
                                                  (unsigned)l2 | ((unsigned)l3 << 16));
        }
#pragma unroll
        for (int kk = bk0; kk < 32; kk += BKS) {
            float4 v = *(const float4*)&B[(size_t)(k0 + kk) * Nc + bn + bcf4];
            unsigned short h, l;
            split_bf(v.x, h, l); BsH[bcf4 + 0][kk] = h; BsL[bcf4 + 0][kk] = l;
            split_bf(v.y, h, l); BsH[bcf4 + 1][kk] = h; BsL[bcf4 + 1][kk] = l;
            split_bf(v.z, h, l); BsH[bcf4 + 2][kk] = h; BsL[bcf4 + 2][kk] = l;
            split_bf(v.w, h, l); BsH[bcf4 + 3][kk] = h; BsL[bcf4 + 3][kk] = l;
        }
        __syncthreads();

        bf16x8 aH[2], aL[2];
#pragma unroll
        for (int rt = 0; rt < 2; ++rt) {
            aH[rt] = *(const bf16x8*)&AsH[w * 32 + rt * 16 + r16][kg * 8];
            aL[rt] = *(const bf16x8*)&AsL[w * 32 + rt * 16 + r16][kg * 8];
        }
#pragma unroll
        for (int ct = 0; ct < CT; ++ct) {
            const bf16x8 bH = *(const bf16x8*)&BsH[ct * 16 + r16][kg * 8];
            const bf16x8 bL = *(const bf16x8*)&BsL[ct * 16 + r16][kg * 8];
#pragma unroll
            for (int rt = 0; rt < 2; ++rt) {
                acc[rt][ct] = __builtin_amdgcn_mfma_f32_16x16x32_bf16(aH[rt], bH, acc[rt][ct], 0, 0, 0);
                acc[rt][ct] = __builtin_amdgcn_mfma_f32_16x16x32_bf16(aH[rt], bL, acc[rt][ct], 0, 0, 0);
                acc[rt][ct] = __builtin_amdgcn_mfma_f32_16x16x32_bf16(aL[rt], bH, acc[rt][ct], 0, 0, 0);
            }
        }
        __syncthreads();
    }

#pragma unroll
    for (int rt = 0; rt < 2; ++rt)
#pragma unroll
        for (int r = 0; r < 4; ++r) {
            int row = bm + w * 32 + rt * 16 + kg * 4 + r;
            if (row < M) {
#pragma unroll
                for (int ct = 0; ct < CT; ++ct)
                    C[(size_t)row * Nc + bn + ct * 16 + r16] = (_Float16)acc[rt][ct][r];
            }
        }
}

// ---------------- layer 0 edge kernel: fp16 gathers, 4-edge unroll ----------------
// Wave per node. lane = head*16+sub; lane owns dims [head*64+sub*4 .. +3].

__global__ __launch_bounds__(256) void gat_edge0(const _Float16* __restrict__ feat,
                                                 const float* __restrict__ attn,
                                                 const int* __restrict__ rowptr,
                                                 const int* __restrict__ csr,
                                                 _Float16* __restrict__ out) {
    const int lane = threadIdx.x & 63;
    const int node = blockIdx.x * 4 + (threadIdx.x >> 6);
    if (node >= N_NODES) return;
    const int dbase = ((lane >> 4) << 6) + (lane & 15) * 4;
    const float4 a = *(const float4*)&attn[dbase];
    const half4v fdh = *(const half4v*)&feat[(size_t)node * 256 + dbase];
    const float fdx = (float)fdh[0], fdy = (float)fdh[1], fdz = (float)fdh[2], fdw = (float)fdh[3];
    const int beg = rowptr[node], end = rowptr[node + 1];
    float m = -1e30f, s = 0.f;
    float ax = 0.f, ay = 0.f, az = 0.f, aw = 0.f;
    int j = beg;
    for (; j + 3 < end; j += 4) {
        int sn0 = csr[j], sn1 = csr[j + 1], sn2 = csr[j + 2], sn3 = csr[j + 3];
        half4v h0 = *(const half4v*)&feat[(size_t)sn0 * 256 + dbase];
        half4v h1 = *(const half4v*)&feat[(size_t)sn1 * 256 + dbase];
        half4v h2 = *(const half4v*)&feat[(size_t)sn2 * 256 + dbase];
        half4v h3 = *(const half4v*)&feat[(size_t)sn3 * 256 + dbase];
        float f0x = (float)h0[0], f0y = (float)h0[1], f0z = (float)h0[2], f0w = (float)h0[3];
        float f1x = (float)h1[0], f1y = (float)h1[1], f1z = (float)h1[2], f1w = (float)h1[3];
        float f2x = (float)h2[0], f2y = (float)h2[1], f2z = (float)h2[2], f2w = (float)h2[3];
        float f3x = (float)h3[0], f3y = (float)h3[1], f3z = (float)h3[2], f3w = (float)h3[3];
        float p0 = lrelu(f0x + fdx) * a.x + lrelu(f0y + fdy) * a.y + lrelu(f0z + fdz) * a.z + lrelu(f0w + fdw) * a.w;
        float p1 = lrelu(f1x + fdx) * a.x + lrelu(f1y + fdy) * a.y + lrelu(f1z + fdz) * a.z + lrelu(f1w + fdw) * a.w;
        float p2 = lrelu(f2x + fdx) * a.x + lrelu(f2y + fdy) * a.y + lrelu(f2z + fdz) * a.z + lrelu(f2w + fdw) * a.w;
        float p3 = lrelu(f3x + fdx) * a.x + lrelu(f3y + fdy) * a.y + lrelu(f3z + fdz) * a.z + lrelu(f3w + fdw) * a.w;
        p0 += __shfl_xor(p0, 1); p1 += __shfl_xor(p1, 1); p2 += __shfl_xor(p2, 1); p3 += __shfl_xor(p3, 1);
        p0 += __shfl_xor(p0, 2); p1 += __shfl_xor(p1, 2); p2 += __shfl_xor(p2, 2); p3 += __shfl_xor(p3, 2);
        p0 += __shfl_xor(p0, 4); p1 += __shfl_xor(p1, 4); p2 += __shfl_xor(p2, 4); p3 += __shfl_xor(p3, 4);
        p0 += __shfl_xor(p0, 8); p1 += __shfl_xor(p1, 8); p2 += __shfl_xor(p2, 8); p3 += __shfl_xor(p3, 8);
        float nm = fmaxf(fmaxf(m, fmaxf(p0, p1)), fmaxf(p2, p3));
        float c  = __expf(m - nm);
        float e0 = __expf(p0 - nm);
        float e1 = __expf(p1 - nm);
        float e2 = __expf(p2 - nm);
        float e3 = __expf(p3 - nm);
        s  = s  * c + e0 + e1 + e2 + e3;
        ax = ax * c + e0 * f0x + e1 * f1x + e2 * f2x + e3 * f3x;
        ay = ay * c + e0 * f0y + e1 * f1y + e2 * f2y + e3 * f3y;
        az = az * c + e0 * f0z + e1 * f1z + e2 * f2z + e3 * f3z;
        aw = aw * c + e0 * f0w + e1 * f1w + e2 * f2w + e3 * f3w;
        m = nm;
    }
    for (; j < end; ++j) {
        int sn = csr[j];
        half4v hv = *(const half4v*)&feat[(size_t)sn * 256 + dbase];
        float fx = (float)hv[0], fy = (float)hv[1], fz = (float)hv[2], fw = (float)hv[3];
        float p = lrelu(fx + fdx) * a.x + lrelu(fy + fdy) * a.y + lrelu(fz + fdz) * a.z + lrelu(fw + fdw) * a.w;
        p += __shfl_xor(p, 1);
        p += __shfl_xor(p, 2);
        p += __shfl_xor(p, 4);
        p += __shfl_xor(p, 8);
        float nm = fmaxf(m, p);
        float c  = __expf(m - nm);
        float e  = __expf(p - nm);
        s  = s  * c + e;
        ax = ax * c + e * fx;
        ay = ay * c + e * fy;
        az = az * c + e * fz;
        aw = aw * c + e * fw;
        m = nm;
    }
    float inv = (end > beg) ? (1.0f / s) : 0.f;
    float v;
    half4v o;
    v = ax * inv; o[0] = (_Float16)((v > 0.f) ? v : (__expf(v) - 1.f));
    v = ay * inv; o[1] = (_Float16)((v > 0.f) ? v : (__expf(v) - 1.f));
    v = az * inv; o[2] = (_Float16)((v > 0.f) ? v : (__expf(v) - 1.f));
    v = aw * inv; o[3] = (_Float16)((v > 0.f) ? v : (__expf(v) - 1.f));
    *(half4v*)&out[(size_t)node * 256 + dbase] = o;
}

// ---------------- layer 1 edge kernel: 4 edges in flight (one per 16-lane group) ----
// Wave per node; group g = lane>>4 processes edges beg+g, beg+g+4, ...
// Lane sub=lane&15 owns dims [sub*4 .. +3]. Group-local online softmax, then
// 2-round cross-group merge. Output f32.

__global__ __launch_bounds__(256) void gat_edge1(const _Float16* __restrict__ feat,
                                                 const float* __restrict__ attn,
                                                 const int* __restrict__ rowptr,
                                                 const int* __restrict__ csr,
                                                 float* __restrict__ out) {
    const int lane = threadIdx.x & 63;
    const int node = blockIdx.x * 4 + (threadIdx.x >> 6);
    if (node >= N_NODES) return;
    const int g = lane >> 4;
    const int d0 = (lane & 15) * 4;
    const float4 a = *(const float4*)&attn[d0];
    const half4v fdh = *(const half4v*)&feat[(size_t)node * 64 + d0];
    const float fdx = (float)fdh[0], fdy = (float)fdh[1], fdz = (float)fdh[2], fdw = (float)fdh[3];
    const int beg = rowptr[node], end = rowptr[node + 1];
    float m = -1e30f, s = 0.f;
    float ax = 0.f, ay = 0.f, az = 0.f, aw = 0.f;
    for (int j = beg + g; j < end; j += 4) {
        int sn = csr[j];
        half4v hv = *(const half4v*)&feat[(size_t)sn * 64 + d0];
        float fx = (float)hv[0], fy = (float)hv[1], fz = (float)hv[2], fw = (float)hv[3];
        float p = lrelu(fx + fdx) * a.x + lrelu(fy + fdy) * a.y + lrelu(fz + fdz) * a.z + lrelu(fw + fdw) * a.w;
        p += __shfl_xor(p, 1);
        p += __shfl_xor(p, 2);
        p += __shfl_xor(p, 4);
        p += __shfl_xor(p, 8);
        float nm = fmaxf(m, p);
        float c  = __expf(m - nm);
        float e  = __expf(p - nm);
        s  = s  * c + e;
        ax = ax * c + e * fx;
        ay = ay * c + e * fy;
        az = az * c + e * fz;
        aw = aw * c + e * fw;
        m = nm;
    }
    // merge the 4 group-local softmax states
#pragma unroll
    for (int off = 16; off <= 32; off <<= 1) {
        float mo = __shfl_xor(m, off);
        float so = __shfl_xor(s, off);
        float bx = __shfl_xor(ax, off);
        float by = __shfl_xor(ay, off);
        float bz = __shfl_xor(az, off);
        float bw = __shfl_xor(aw, off);
        float nm = fmaxf(m, mo);
        float c  = __expf(m - nm);
        float co = __expf(mo - nm);
        s  = s  * c + so * co;
        ax = ax * c + bx * co;
        ay = ay * c + by * co;
        az = az * c + bz * co;
        aw = aw * c + bw * co;
        m = nm;
    }
    if (g == 0) {
        float inv = (end > beg) ? (1.0f / s) : 0.f;
        float4 o = make_float4(ax * inv, ay * inv, az * inv, aw * inv);
        *(float4*)&out[(size_t)node * 64 + d0] = o;
    }
}

// ---------------- launch ----------------

extern "C" void kernel_launch(void* const* d_in, const int* in_sizes, int n_in,
                              void* d_out, int out_size, void* d_ws, size_t ws_size,
                              hipStream_t stream) {
    const float* x     = (const float*)d_in[0];
    const float* W0    = (const float*)d_in[1];
    const float* attn0 = (const float*)d_in[2];
    const float* W1    = (const float*)d_in[3];
    const float* attn1 = (const float*)d_in[4];
    const int*   src0  = (const int*)d_in[5];
    const int*   dst0  = (const int*)d_in[6];
    const int*   src1  = (const int*)d_in[7];
    const int*   dst1  = (const int*)d_in[8];
    float* out = (float*)d_out;

    _Float16* feat0h = (_Float16*)d_ws;                        // N*256 fp16
    _Float16* h0h    = feat0h + (size_t)N_NODES * 256;         // N*256 fp16
    _Float16* feat1h = h0h + (size_t)N_NODES * 256;            // N*64  fp16
    int* deg    = (int*)(feat1h + (size_t)N_NODES * 64);       // 2N
    int* rowptr = deg + 2 * N_NODES;                           // 2(N+1)
    int* cursor = rowptr + 2 * (N_NODES + 1);                  // 2N
    int* bsum   = cursor + 2 * N_NODES;                        // 2*256
    int* boff   = bsum + 512;                                  // 2*256
    int* csr0   = boff + 512;                                  // E
    int* csr1   = csr0 + E_EDGES;                              // E

    const int nb = (N_NODES + 255) / 256;  // 196
    const int eb = (E_EDGES + 255) / 256;  // 3125

    // ---- CSR for both layers (independent of GEMMs) ----
    hipMemsetAsync(deg, 0, 2 * N_NODES * sizeof(int), stream);
    k_hist2<<<dim3(eb, 2), 256, 0, stream>>>(dst0, dst1, deg);
    k_scanA<<<dim3(nb, 2), 256, 0, stream>>>(deg, rowptr, bsum);
    k_scanB<<<2, 256, 0, stream>>>(bsum, boff, nb);
    k_scanC<<<dim3(nb, 2), 256, 0, stream>>>(deg, boff, rowptr, cursor);
    k_scatter2<<<dim3(eb, 2), 256, 0, stream>>>(src0, dst0, src1, dst1, cursor, csr0, csr1);

    // ---- layer 0 ----
    mfma_gemm<128, false><<<dim3(391, 2), 256, 0, stream>>>(x, W0, feat0h, N_NODES, 256);
    gat_edge0<<<(N_NODES + 3) / 4, 256, 0, stream>>>(feat0h, attn0, rowptr, csr0, h0h);

    // ---- layer 1 ----
    mfma_gemm<64, true><<<dim3(391, 1), 256, 0, stream>>>(h0h, W1, feat1h, N_NODES, 64);
    gat_edge1<<<(N_NODES + 3) / 4, 256, 0, stream>>>(feat1h, attn1,
                                                     rowptr + (N_NODES + 1), csr1, out);
}

// Round 5
// 398.807 us; speedup vs baseline: 3.9199x; 1.0529x over previous
//
#include <hip/hip_runtime.h>

#define N_NODES 50000
#define E_EDGES 800000
#define NEG_SLOPE 0.2f
#define NSL 8
#define SLN (NSL * N_NODES)          // 400000
#define NB1 196                      // ceil(N/256)
#define NB2 1563                     // ceil(8N/256)

typedef __attribute__((ext_vector_type(8))) short bf16x8;
typedef __attribute__((ext_vector_type(4))) float f32x4;
typedef __attribute__((ext_vector_type(4))) _Float16 half4v;

// truncate-split: f ~= hi + lo with |err| <= 2^-16 |f|
__device__ __forceinline__ void split_bf(float f, unsigned short& h, unsigned short& l) {
    unsigned u = __float_as_uint(f);
    h = (unsigned short)(u >> 16);
    float r = f - __uint_as_float((unsigned)h << 16);
    l = (unsigned short)(__float_as_uint(r) >> 16);
}

__device__ __forceinline__ float lrelu(float t) { return (t > 0.f) ? t : NEG_SLOPE * t; }

// ---------------- CSR build: slice-local scatter + regroup ----------------
// deg_s[layer][slice][node]; slice = blockIdx.x & 7 (XCD round-robin heuristic).

__global__ void k_hist(const int* __restrict__ dst0, const int* __restrict__ dst1,
                       int* __restrict__ deg_s) {
    const int layer = blockIdx.y;
    const int slice = blockIdx.x & (NSL - 1);
    int i = blockIdx.x * blockDim.x + threadIdx.x;
    if (i >= E_EDGES) return;
    int d = (layer == 0) ? dst0[i] : dst1[i];
    atomicAdd(&deg_s[layer * SLN + slice * N_NODES + d], 1);
}

// scan1: rowptr over per-node totals (sum of 8 slices)
__global__ void k_scan1A(const int* __restrict__ deg_s, int* __restrict__ rowptr,
                         int* __restrict__ bsum) {
    const int layer = blockIdx.y;
    __shared__ int lds[256];
    int t = threadIdx.x;
    int i = blockIdx.x * 256 + t;
    int v = 0;
    if (i < N_NODES) {
        const int* d = deg_s + layer * SLN + i;
#pragma unroll
        for (int s = 0; s < NSL; ++s) v += d[s * N_NODES];
    }
    lds[t] = v;
    __syncthreads();
    for (int off = 1; off < 256; off <<= 1) {
        int u = (t >= off) ? lds[t - off] : 0;
        __syncthreads();
        lds[t] += u;
        __syncthreads();
    }
    if (i < N_NODES) rowptr[layer * (N_NODES + 1) + i + 1] = lds[t];
    if (t == 255) bsum[layer * 256 + blockIdx.x] = lds[255];
}

__global__ void k_scanB(const int* __restrict__ bsum, int* __restrict__ boff, int nb) {
    const int layer = blockIdx.x;
    const int* bs = bsum + layer * 256;
    int* bo = boff + layer * 256;
    __shared__ int lds[256];
    int t = threadIdx.x;
    int v = (t < nb) ? bs[t] : 0;
    lds[t] = v;
    __syncthreads();
    for (int off = 1; off < 256; off <<= 1) {
        int u = (t >= off) ? lds[t - off] : 0;
        __syncthreads();
        lds[t] += u;
        __syncthreads();
    }
    if (t < nb) bo[t] = lds[t] - v;
}

__global__ void k_scan1C(const int* __restrict__ boff, int* __restrict__ rowptr) {
    const int layer = blockIdx.y;
    int i = blockIdx.x * blockDim.x + threadIdx.x;
    if (i >= N_NODES) return;
    int* rp = rowptr + layer * (N_NODES + 1);
    rp[i + 1] += boff[layer * 256 + (i >> 8)];
    if (i == 0) rp[0] = 0;
}

// scan2: flattened slice-major scan over deg_s[8N] -> rowptr_s (tmp bases)
__global__ void k_scan2A(const int* __restrict__ deg_s, int* __restrict__ rowptr_s,
                         int* __restrict__ bsum2) {
    const int layer = blockIdx.y;
    __shared__ int lds[256];
    int t = threadIdx.x;
    int i = blockIdx.x * 256 + t;
    int v = (i < SLN) ? deg_s[layer * SLN + i] : 0;
    lds[t] = v;
    __syncthreads();
    for (int off = 1; off < 256; off <<= 1) {
        int u = (t >= off) ? lds[t - off] : 0;
        __syncthreads();
        lds[t] += u;
        __syncthreads();
    }
    if (i < SLN) rowptr_s[layer * SLN + i] = lds[t];   // inclusive, pre-boff
    if (t == 255) bsum2[layer * NB2 + blockIdx.x] = lds[255];
}

__global__ void k_scan2B(const int* __restrict__ bsum2, int* __restrict__ boff2) {
    const int layer = blockIdx.x;
    __shared__ int lds[256];
    __shared__ int carry;
    int t = threadIdx.x;
    if (t == 0) carry = 0;
    __syncthreads();
    for (int c = 0; c < NB2; c += 256) {
        int v = (c + t < NB2) ? bsum2[layer * NB2 + c + t] : 0;
        lds[t] = v;
        __syncthreads();
        for (int off = 1; off < 256; off <<= 1) {
            int u = (t >= off) ? lds[t - off] : 0;
            __syncthreads();
            lds[t] += u;
            __syncthreads();
        }
        if (c + t < NB2) boff2[layer * NB2 + c + t] = carry + lds[t] - v;
        __syncthreads();
        if (t == 255) carry += lds[255];
        __syncthreads();
    }
}

__global__ void k_scan2C(const int* __restrict__ deg_s, const int* __restrict__ boff2,
                         int* __restrict__ rowptr_s, int* __restrict__ cursor_s) {
    const int layer = blockIdx.y;
    int i = blockIdx.x * 256 + threadIdx.x;
    if (i >= SLN) return;
    const int base = layer * SLN;
    int b = rowptr_s[base + i] + boff2[layer * NB2 + (i >> 8)] - deg_s[base + i];
    rowptr_s[base + i] = b;   // exclusive base of (slice,node) sub-segment in tmp
    cursor_s[base + i] = b;
}

__global__ void k_scatter(const int* __restrict__ src0, const int* __restrict__ dst0,
                          const int* __restrict__ src1, const int* __restrict__ dst1,
                          int* __restrict__ cursor_s, int* __restrict__ tmp) {
    const int layer = blockIdx.y;
    const int slice = blockIdx.x & (NSL - 1);
    int i = blockIdx.x * blockDim.x + threadIdx.x;
    if (i >= E_EDGES) return;
    int s, d;
    if (layer == 0) { s = src0[i]; d = dst0[i]; }
    else            { s = src1[i]; d = dst1[i]; }
    int pos = atomicAdd(&cursor_s[layer * SLN + slice * N_NODES + d], 1);
    tmp[layer * E_EDGES + pos] = s;
}

// wave per node: copy its 8 slice sub-segments from tmp into node-major csr
__global__ __launch_bounds__(256) void k_regroup(const int* __restrict__ deg_s,
                                                 const int* __restrict__ rowptr_s,
                                                 const int* __restrict__ rowptr,
                                                 const int* __restrict__ tmp,
                                                 int* __restrict__ csr) {
    const int layer = blockIdx.y;
    const int lane = threadIdx.x & 63;
    const int node = blockIdx.x * 4 + (threadIdx.x >> 6);
    if (node >= N_NODES) return;
    const int base = layer * SLN;
    int dg = 0, tb = 0;
    if (lane < NSL) {
        dg = deg_s[base + lane * N_NODES + node];
        tb = rowptr_s[base + lane * N_NODES + node];
    }
    // exclusive prefix of dg over lanes 0..7 + total
    int excl = 0, total = 0;
#pragma unroll
    for (int ss = 0; ss < NSL; ++ss) {
        int v = __shfl(dg, ss);
        if (ss < (lane & 7)) excl += v;
        total += v;
    }
    const int base_out = rowptr[layer * (N_NODES + 1) + node];
    const int* tsrc = tmp + (size_t)layer * E_EDGES;
    int* cdst = csr + (size_t)layer * E_EDGES;
    for (int r0 = 0; r0 < total; r0 += 64) {
        int r = r0 + lane;
        bool active = (r < total);
        int rr = active ? r : 0;
        int s = 0;
#pragma unroll
        for (int ss = 1; ss < NSL; ++ss) {
            int e = __shfl(excl, ss);
            if (rr >= e) s = ss;
        }
        int eS  = __shfl(excl, s);
        int tbS = __shfl(tb, s);
        if (active) cdst[base_out + r] = tsrc[tbS + (r - eS)];
    }
}

// ---------------- split-bf16 MFMA GEMM, fp16 output table ----------------

template<int BN, bool AHALF>
__global__ __launch_bounds__(256) void mfma_gemm(const void* __restrict__ Av,
                                                 const float* __restrict__ B,
                                                 _Float16* __restrict__ C,
                                                 int M, int Nc) {
    constexpr int K = 256;
    constexpr int CT = BN / 16;
    constexpr int BF4 = BN / 4;
    constexpr int BKS = 256 / BF4;
    __shared__ __align__(16) unsigned short AsH[128][40];
    __shared__ __align__(16) unsigned short AsL[128][40];
    __shared__ __align__(16) unsigned short BsH[BN][40];
    __shared__ __align__(16) unsigned short BsL[BN][40];

    const int t = threadIdx.x;
    const int w = t >> 6;
    const int lane = t & 63;
    const int r16 = lane & 15;
    const int kg = lane >> 4;
    const int bm = blockIdx.x * 128;
    const int bn = blockIdx.y * BN;

    const int ar0 = t >> 3;
    const int acol = (t & 7) * 4;
    const int bcf4 = (t % BF4) * 4;
    const int bk0 = t / BF4;

    f32x4 acc[2][CT];
#pragma unroll
    for (int i = 0; i < 2; ++i)
#pragma unroll
        for (int j = 0; j < CT; ++j) acc[i][j] = (f32x4){0.f, 0.f, 0.f, 0.f};

    for (int k0 = 0; k0 < K; k0 += 32) {
#pragma unroll
        for (int rr = 0; rr < 4; ++rr) {
            int row = ar0 + 32 * rr;
            int grow = bm + row;
            float4 v = make_float4(0.f, 0.f, 0.f, 0.f);
            if (grow < M) {
                if constexpr (AHALF) {
                    const _Float16* A = (const _Float16*)Av;
                    half4v hv = *(const half4v*)&A[(size_t)grow * K + k0 + acol];
                    v = make_float4((float)hv[0], (float)hv[1], (float)hv[2], (float)hv[3]);
                } else {
                    const float* A = (const float*)Av;
                    v = *(const float4*)&A[(size_t)grow * K + k0 + acol];
                }
            }
            unsigned short h0, h1, h2, h3, l0, l1, l2, l3;
            split_bf(v.x, h0, l0); split_bf(v.y, h1, l1);
            split_bf(v.z, h2, l2); split_bf(v.w, h3, l3);
            *(uint2*)&AsH[row][acol] = make_uint2((unsigned)h0 | ((unsigned)h1 << 16),
                                                  (unsigned)h2 | ((unsigned)h3 << 16));
            *(uint2*)&AsL[row][acol] = make_uint2((unsigned)l0 | ((unsigned)l1 << 16),
                                                  (unsigned)l2 | ((unsigned)l3 << 16));
        }
#pragma unroll
        for (int kk = bk0; kk < 32; kk += BKS) {
            float4 v = *(const float4*)&B[(size_t)(k0 + kk) * Nc + bn + bcf4];
            unsigned short h, l;
            split_bf(v.x, h, l); BsH[bcf4 + 0][kk] = h; BsL[bcf4 + 0][kk] = l;
            split_bf(v.y, h, l); BsH[bcf4 + 1][kk] = h; BsL[bcf4 + 1][kk] = l;
            split_bf(v.z, h, l); BsH[bcf4 + 2][kk] = h; BsL[bcf4 + 2][kk] = l;
            split_bf(v.w, h, l); BsH[bcf4 + 3][kk] = h; BsL[bcf4 + 3][kk] = l;
        }
        __syncthreads();

        bf16x8 aH[2], aL[2];
#pragma unroll
        for (int rt = 0; rt < 2; ++rt) {
            aH[rt] = *(const bf16x8*)&AsH[w * 32 + rt * 16 + r16][kg * 8];
            aL[rt] = *(const bf16x8*)&AsL[w * 32 + rt * 16 + r16][kg * 8];
        }
#pragma unroll
        for (int ct = 0; ct < CT; ++ct) {
            const bf16x8 bH = *(const bf16x8*)&BsH[ct * 16 + r16][kg * 8];
            const bf16x8 bL = *(const bf16x8*)&BsL[ct * 16 + r16][kg * 8];
#pragma unroll
            for (int rt = 0; rt < 2; ++rt) {
                acc[rt][ct] = __builtin_amdgcn_mfma_f32_16x16x32_bf16(aH[rt], bH, acc[rt][ct], 0, 0, 0);
                acc[rt][ct] = __builtin_amdgcn_mfma_f32_16x16x32_bf16(aH[rt], bL, acc[rt][ct], 0, 0, 0);
                acc[rt][ct] = __builtin_amdgcn_mfma_f32_16x16x32_bf16(aL[rt], bH, acc[rt][ct], 0, 0, 0);
            }
        }
        __syncthreads();
    }

#pragma unroll
    for (int rt = 0; rt < 2; ++rt)
#pragma unroll
        for (int r = 0; r < 4; ++r) {
            int row = bm + w * 32 + rt * 16 + kg * 4 + r;
            if (row < M) {
#pragma unroll
                for (int ct = 0; ct < CT; ++ct)
                    C[(size_t)row * Nc + bn + ct * 16 + r16] = (_Float16)acc[rt][ct][r];
            }
        }
}

// ---------------- layer 0 edge kernel: fp16 gathers, 4-edge unroll ----------------

__global__ __launch_bounds__(256) void gat_edge0(const _Float16* __restrict__ feat,
                                                 const float* __restrict__ attn,
                                                 const int* __restrict__ rowptr,
                                                 const int* __restrict__ csr,
                                                 _Float16* __restrict__ out) {
    const int lane = threadIdx.x & 63;
    const int node = blockIdx.x * 4 + (threadIdx.x >> 6);
    if (node >= N_NODES) return;
    const int dbase = ((lane >> 4) << 6) + (lane & 15) * 4;
    const float4 a = *(const float4*)&attn[dbase];
    const half4v fdh = *(const half4v*)&feat[(size_t)node * 256 + dbase];
    const float fdx = (float)fdh[0], fdy = (float)fdh[1], fdz = (float)fdh[2], fdw = (float)fdh[3];
    const int beg = rowptr[node], end = rowptr[node + 1];
    float m = -1e30f, s = 0.f;
    float ax = 0.f, ay = 0.f, az = 0.f, aw = 0.f;
    int j = beg;
    for (; j + 3 < end; j += 4) {
        int sn0 = csr[j], sn1 = csr[j + 1], sn2 = csr[j + 2], sn3 = csr[j + 3];
        half4v h0 = *(const half4v*)&feat[(size_t)sn0 * 256 + dbase];
        half4v h1 = *(const half4v*)&feat[(size_t)sn1 * 256 + dbase];
        half4v h2 = *(const half4v*)&feat[(size_t)sn2 * 256 + dbase];
        half4v h3 = *(const half4v*)&feat[(size_t)sn3 * 256 + dbase];
        float f0x = (float)h0[0], f0y = (float)h0[1], f0z = (float)h0[2], f0w = (float)h0[3];
        float f1x = (float)h1[0], f1y = (float)h1[1], f1z = (float)h1[2], f1w = (float)h1[3];
        float f2x = (float)h2[0], f2y = (float)h2[1], f2z = (float)h2[2], f2w = (float)h2[3];
        float f3x = (float)h3[0], f3y = (float)h3[1], f3z = (float)h3[2], f3w = (float)h3[3];
        float p0 = lrelu(f0x + fdx) * a.x + lrelu(f0y + fdy) * a.y + lrelu(f0z + fdz) * a.z + lrelu(f0w + fdw) * a.w;
        float p1 = lrelu(f1x + fdx) * a.x + lrelu(f1y + fdy) * a.y + lrelu(f1z + fdz) * a.z + lrelu(f1w + fdw) * a.w;
        float p2 = lrelu(f2x + fdx) * a.x + lrelu(f2y + fdy) * a.y + lrelu(f2z + fdz) * a.z + lrelu(f2w + fdw) * a.w;
        float p3 = lrelu(f3x + fdx) * a.x + lrelu(f3y + fdy) * a.y + lrelu(f3z + fdz) * a.z + lrelu(f3w + fdw) * a.w;
        p0 += __shfl_xor(p0, 1); p1 += __shfl_xor(p1, 1); p2 += __shfl_xor(p2, 1); p3 += __shfl_xor(p3, 1);
        p0 += __shfl_xor(p0, 2); p1 += __shfl_xor(p1, 2); p2 += __shfl_xor(p2, 2); p3 += __shfl_xor(p3, 2);
        p0 += __shfl_xor(p0, 4); p1 += __shfl_xor(p1, 4); p2 += __shfl_xor(p2, 4); p3 += __shfl_xor(p3, 4);
        p0 += __shfl_xor(p0, 8); p1 += __shfl_xor(p1, 8); p2 += __shfl_xor(p2, 8); p3 += __shfl_xor(p3, 8);
        float nm = fmaxf(fmaxf(m, fmaxf(p0, p1)), fmaxf(p2, p3));
        float c  = __expf(m - nm);
        float e0 = __expf(p0 - nm);
        float e1 = __expf(p1 - nm);
        float e2 = __expf(p2 - nm);
        float e3 = __expf(p3 - nm);
        s  = s  * c + e0 + e1 + e2 + e3;
        ax = ax * c + e0 * f0x + e1 * f1x + e2 * f2x + e3 * f3x;
        ay = ay * c + e0 * f0y + e1 * f1y + e2 * f2y + e3 * f3y;
        az = az * c + e0 * f0z + e1 * f1z + e2 * f2z + e3 * f3z;
        aw = aw * c + e0 * f0w + e1 * f1w + e2 * f2w + e3 * f3w;
        m = nm;
    }
    for (; j < end; ++j) {
        int sn = csr[j];
        half4v hv = *(const half4v*)&feat[(size_t)sn * 256 + dbase];
        float fx = (float)hv[0], fy = (float)hv[1], fz = (float)hv[2], fw = (float)hv[3];
        float p = lrelu(fx + fdx) * a.x + lrelu(fy + fdy) * a.y + lrelu(fz + fdz) * a.z + lrelu(fw + fdw) * a.w;
        p += __shfl_xor(p, 1);
        p += __shfl_xor(p, 2);
        p += __shfl_xor(p, 4);
        p += __shfl_xor(p, 8);
        float nm = fmaxf(m, p);
        float c  = __expf(m - nm);
        float e  = __expf(p - nm);
        s  = s  * c + e;
        ax = ax * c + e * fx;
        ay = ay * c + e * fy;
        az = az * c + e * fz;
        aw = aw * c + e * fw;
        m = nm;
    }
    float inv = (end > beg) ? (1.0f / s) : 0.f;
    float v;
    half4v o;
    v = ax * inv; o[0] = (_Float16)((v > 0.f) ? v : (__expf(v) - 1.f));
    v = ay * inv; o[1] = (_Float16)((v > 0.f) ? v : (__expf(v) - 1.f));
    v = az * inv; o[2] = (_Float16)((v > 0.f) ? v : (__expf(v) - 1.f));
    v = aw * inv; o[3] = (_Float16)((v > 0.f) ? v : (__expf(v) - 1.f));
    *(half4v*)&out[(size_t)node * 256 + dbase] = o;
}

// ---------------- layer 1 edge kernel: 4 edges in flight ----------------

__global__ __launch_bounds__(256) void gat_edge1(const _Float16* __restrict__ feat,
                                                 const float* __restrict__ attn,
                                                 const int* __restrict__ rowptr,
                                                 const int* __restrict__ csr,
                                                 float* __restrict__ out) {
    const int lane = threadIdx.x & 63;
    const int node = blockIdx.x * 4 + (threadIdx.x >> 6);
    if (node >= N_NODES) return;
    const int g = lane >> 4;
    const int d0 = (lane & 15) * 4;
    const float4 a = *(const float4*)&attn[d0];
    const half4v fdh = *(const half4v*)&feat[(size_t)node * 64 + d0];
    const float fdx = (float)fdh[0], fdy = (float)fdh[1], fdz = (float)fdh[2], fdw = (float)fdh[3];
    const int beg = rowptr[node], end = rowptr[node + 1];
    float m = -1e30f, s = 0.f;
    float ax = 0.f, ay = 0.f, az = 0.f, aw = 0.f;
    for (int j = beg + g; j < end; j += 4) {
        int sn = csr[j];
        half4v hv = *(const half4v*)&feat[(size_t)sn * 64 + d0];
        float fx = (float)hv[0], fy = (float)hv[1], fz = (float)hv[2], fw = (float)hv[3];
        float p = lrelu(fx + fdx) * a.x + lrelu(fy + fdy) * a.y + lrelu(fz + fdz) * a.z + lrelu(fw + fdw) * a.w;
        p += __shfl_xor(p, 1);
        p += __shfl_xor(p, 2);
        p += __shfl_xor(p, 4);
        p += __shfl_xor(p, 8);
        float nm = fmaxf(m, p);
        float c  = __expf(m - nm);
        float e  = __expf(p - nm);
        s  = s  * c + e;
        ax = ax * c + e * fx;
        ay = ay * c + e * fy;
        az = az * c + e * fz;
        aw = aw * c + e * fw;
        m = nm;
    }
#pragma unroll
    for (int off = 16; off <= 32; off <<= 1) {
        float mo = __shfl_xor(m, off);
        float so = __shfl_xor(s, off);
        float bx = __shfl_xor(ax, off);
        float by = __shfl_xor(ay, off);
        float bz = __shfl_xor(az, off);
        float bw = __shfl_xor(aw, off);
        float nm = fmaxf(m, mo);
        float c  = __expf(m - nm);
        float co = __expf(mo - nm);
        s  = s  * c + so * co;
        ax = ax * c + bx * co;
        ay = ay * c + by * co;
        az = az * c + bz * co;
        aw = aw * c + bw * co;
        m = nm;
    }
    if (g == 0) {
        float inv = (end > beg) ? (1.0f / s) : 0.f;
        float4 o = make_float4(ax * inv, ay * inv, az * inv, aw * inv);
        *(float4*)&out[(size_t)node * 64 + d0] = o;
    }
}

// ---------------- launch ----------------

extern "C" void kernel_launch(void* const* d_in, const int* in_sizes, int n_in,
                              void* d_out, int out_size, void* d_ws, size_t ws_size,
                              hipStream_t stream) {
    const float* x     = (const float*)d_in[0];
    const float* W0    = (const float*)d_in[1];
    const float* attn0 = (const float*)d_in[2];
    const float* W1    = (const float*)d_in[3];
    const float* attn1 = (const float*)d_in[4];
    const int*   src0  = (const int*)d_in[5];
    const int*   dst0  = (const int*)d_in[6];
    const int*   src1  = (const int*)d_in[7];
    const int*   dst1  = (const int*)d_in[8];
    float* out = (float*)d_out;

    _Float16* feat0h = (_Float16*)d_ws;                        // N*256 fp16
    _Float16* h0h    = feat0h + (size_t)N_NODES * 256;         // N*256 fp16
    _Float16* feat1h = h0h + (size_t)N_NODES * 256;            // N*64  fp16
    int* deg_s    = (int*)(feat1h + (size_t)N_NODES * 64);     // 2*8N
    int* rowptr   = deg_s + 2 * SLN;                           // 2*(N+1)
    int* rowptr_s = rowptr + 2 * (N_NODES + 1);                // 2*8N
    int* cursor_s = rowptr_s + 2 * SLN;                        // 2*8N
    int* bsum1    = cursor_s + 2 * SLN;                        // 2*256
    int* boff1    = bsum1 + 512;                               // 2*256
    int* bsum2    = boff1 + 512;                               // 2*NB2
    int* boff2    = bsum2 + 2 * NB2;                           // 2*NB2
    int* tmp      = boff2 + 2 * NB2;                           // 2*E
    int* csr      = tmp + 2 * E_EDGES;                         // 2*E

    const int eb  = E_EDGES / 256;                 // 3125
    const int nb2 = (SLN + 255) / 256;             // 1563

    // ---- CSR build (both layers) ----
    hipMemsetAsync(deg_s, 0, 2 * SLN * sizeof(int), stream);
    k_hist  <<<dim3(eb, 2),  256, 0, stream>>>(dst0, dst1, deg_s);
    k_scan1A<<<dim3(NB1, 2), 256, 0, stream>>>(deg_s, rowptr, bsum1);
    k_scanB <<<2,            256, 0, stream>>>(bsum1, boff1, NB1);
    k_scan1C<<<dim3(NB1, 2), 256, 0, stream>>>(boff1, rowptr);
    k_scan2A<<<dim3(nb2, 2), 256, 0, stream>>>(deg_s, rowptr_s, bsum2);
    k_scan2B<<<2,            256, 0, stream>>>(bsum2, boff2);
    k_scan2C<<<dim3(nb2, 2), 256, 0, stream>>>(deg_s, boff2, rowptr_s, cursor_s);
    k_scatter<<<dim3(eb, 2), 256, 0, stream>>>(src0, dst0, src1, dst1, cursor_s, tmp);
    k_regroup<<<dim3((N_NODES + 3) / 4, 2), 256, 0, stream>>>(deg_s, rowptr_s, rowptr, tmp, csr);

    // ---- layer 0 ----
    mfma_gemm<128, false><<<dim3(391, 2), 256, 0, stream>>>(x, W0, feat0h, N_NODES, 256);
    gat_edge0<<<(N_NODES + 3) / 4, 256, 0, stream>>>(feat0h, attn0, rowptr, csr, h0h);

    // ---- layer 1 ----
    mfma_gemm<64, true><<<dim3(391, 1), 256, 0, stream>>>(h0h, W1, feat1h, N_NODES, 64);
    gat_edge1<<<(N_NODES + 3) / 4, 256, 0, stream>>>(feat1h, attn1,
                                                     rowptr + (N_NODES + 1), csr + E_EDGES, out);
}